// Round 1
// baseline (213.032 us; speedup 1.0000x reference)
//
#include <hip/hip_runtime.h>

#define HDIM 512
#define LDIM 1024
#define BDIM 64

// ---------------------------------------------------------------------------
// Kernel 1: hproj[b,h] = sum_o hidden[b,o] * W[o,h]        (64 x 512 output)
// grid (B, 2), block 256. Thread computes one h; W reads coalesced across h.
// ---------------------------------------------------------------------------
__global__ __launch_bounds__(256) void hproj_kernel(
    const float* __restrict__ hidden, const float* __restrict__ W,
    float* __restrict__ hproj) {
  __shared__ float sh[HDIM];
  const int b   = blockIdx.x;
  const int tid = threadIdx.x;
  sh[tid]       = hidden[b * HDIM + tid];
  sh[tid + 256] = hidden[b * HDIM + tid + 256];
  __syncthreads();

  const int h = blockIdx.y * 256 + tid;
  float a0 = 0.f, a1 = 0.f, a2 = 0.f, a3 = 0.f;
  #pragma unroll 4
  for (int o = 0; o < HDIM; o += 4) {
    a0 += sh[o + 0] * W[(o + 0) * HDIM + h];
    a1 += sh[o + 1] * W[(o + 1) * HDIM + h];
    a2 += sh[o + 2] * W[(o + 2) * HDIM + h];
    a3 += sh[o + 3] * W[(o + 3) * HDIM + h];
  }
  hproj[b * HDIM + h] = (a0 + a1) + (a2 + a3);
}

// ---------------------------------------------------------------------------
// Kernel 2: energies[b,l] = sum_h hproj[b,h] * enc[l,b,h]
// One wave per (l,b) row. enc row (l*B+b)*H is 2KB contiguous:
// lane reads float4 at h=lane*4 and h=256+lane*4 -> perfectly coalesced.
// ---------------------------------------------------------------------------
__global__ __launch_bounds__(256) void energies_kernel(
    const float* __restrict__ enc, const float* __restrict__ hproj,
    float* __restrict__ energies) {
  const int wave = blockIdx.x * 4 + (threadIdx.x >> 6);  // == l*B + b
  const int lane = threadIdx.x & 63;
  const int b = wave & (BDIM - 1);

  const float4* row = (const float4*)(enc + (size_t)wave * HDIM);
  const float4* hp  = (const float4*)(hproj + b * HDIM);

  float4 e0 = row[lane];
  float4 e1 = row[lane + 64];
  float4 h0 = hp[lane];
  float4 h1 = hp[lane + 64];

  float s = e0.x * h0.x + e0.y * h0.y + e0.z * h0.z + e0.w * h0.w +
            e1.x * h1.x + e1.y * h1.y + e1.z * h1.z + e1.w * h1.w;

  #pragma unroll
  for (int off = 32; off > 0; off >>= 1) s += __shfl_down(s, off, 64);

  if (lane == 0) {
    const int l = wave >> 6;  // wave / B
    energies[b * LDIM + l] = s;
  }
}

// ---------------------------------------------------------------------------
// Kernel 3: row softmax over L=1024, one block (256 thr) per b.
// out[b,0,l] = softmax(energies[b,:])[l]
// ---------------------------------------------------------------------------
__global__ __launch_bounds__(256) void softmax_kernel(
    const float* __restrict__ energies, float* __restrict__ out) {
  const int b    = blockIdx.x;
  const int tid  = threadIdx.x;
  const int wid  = tid >> 6;
  const int lane = tid & 63;

  float4 v = ((const float4*)(energies + b * LDIM))[tid];

  // --- max reduce ---
  float m = fmaxf(fmaxf(v.x, v.y), fmaxf(v.z, v.w));
  #pragma unroll
  for (int off = 32; off > 0; off >>= 1) m = fmaxf(m, __shfl_xor(m, off, 64));
  __shared__ float sm[4];
  if (lane == 0) sm[wid] = m;
  __syncthreads();
  m = fmaxf(fmaxf(sm[0], sm[1]), fmaxf(sm[2], sm[3]));

  // --- exp + sum reduce ---
  float e0 = __expf(v.x - m), e1 = __expf(v.y - m);
  float e2 = __expf(v.z - m), e3 = __expf(v.w - m);
  float s = (e0 + e1) + (e2 + e3);
  #pragma unroll
  for (int off = 32; off > 0; off >>= 1) s += __shfl_xor(s, off, 64);
  __shared__ float ss[4];
  if (lane == 0) ss[wid] = s;
  __syncthreads();
  s = (ss[0] + ss[1]) + (ss[2] + ss[3]);

  const float inv = 1.0f / s;
  float4 o4 = make_float4(e0 * inv, e1 * inv, e2 * inv, e3 * inv);
  ((float4*)(out + b * LDIM))[tid] = o4;
}

extern "C" void kernel_launch(void* const* d_in, const int* in_sizes, int n_in,
                              void* d_out, int out_size, void* d_ws, size_t ws_size,
                              hipStream_t stream) {
  const float* hidden = (const float*)d_in[0];  // [1,B,H]
  const float* enc    = (const float*)d_in[1];  // [L,B,H]
  const float* W      = (const float*)d_in[2];  // [H,H] (o-major)
  // d_in[3] = bias: constant along softmax axis after the dot -> dropped.

  float* out      = (float*)d_out;              // [B,1,L]
  float* hproj    = (float*)d_ws;                               // 64*512*4   = 128 KB
  float* energies = (float*)((char*)d_ws + BDIM * HDIM * 4);    // 64*1024*4  = 256 KB

  hproj_kernel<<<dim3(BDIM, 2), 256, 0, stream>>>(hidden, W, hproj);
  energies_kernel<<<(LDIM * BDIM) / 4, 256, 0, stream>>>(enc, hproj, energies);
  softmax_kernel<<<BDIM, 256, 0, stream>>>(energies, out);
}